// Round 13
// baseline (997.481 us; speedup 1.0000x reference)
//
#include <hip/hip_runtime.h>
#include <hip/hip_bf16.h>

// Sparse BasicBlock: conv1 -> BN1 -> ReLU -> conv2 -> BN2 -> +x -> ReLU
// Chunked atomic-free formulation (ws-adaptive), consolidated best-known:
//   prep_xw: x->bf16, W->bf16^T
//   rank_count: counting-sort ranks + (k,chunk) bin histogram (fused, atomic last)
//   scans/bin_fill: compact per-(k,chunk) records (perm inline)
//   per chunk: phaseA = gather bf16 -> MFMA -> write-once msg row (TPB=8)
//              phaseB = wide segment-sum (8rows x 8ch lanes, 2x unroll) + BN partials
// Fallback: atomic-scatter path if ws_size too small.

#define NNODES 262144
#define NC 64
#define NK 27
#define NP 131072            // pairs per k (2^17)
#define NPAIR (NK * NP)
#define EPSV 1e-5f
#define TILE 64
#define TPB 8
#define BGRID 4096           // phaseB blocks (also psum rows)

typedef float f32x4 __attribute__((ext_vector_type(4)));
typedef __bf16 bf16x8 __attribute__((ext_vector_type(8)));

// ---------------------------------------------------------------- prep: W -> bf16 transposed (fallback)
__global__ void prep_w(const float* __restrict__ W, __bf16* __restrict__ Wt) {
    int i = blockIdx.x * 256 + threadIdx.x;
    if (i >= NK * NC * NC) return;
    int k  = i >> 12;
    int n  = (i >> 6) & 63;
    int ci = i & 63;
    Wt[i] = (__bf16)W[k * 4096 + ci * 64 + n];
}

// ---------------------------------------------------------------- prep: x->bf16 + W1/W2->bf16^T
#define BXG 8192             // NNODES*64/8/256
#define BWG 864              // 2*NK*4096/256
__global__ __launch_bounds__(256)
void prep_xw(const float* __restrict__ X, __bf16* __restrict__ Xb,
             const float* __restrict__ W1, const float* __restrict__ W2,
             __bf16* __restrict__ Wt1, __bf16* __restrict__ Wt2) {
    const int b = blockIdx.x;
    const int t = threadIdx.x;
    if (b < BXG) {
        size_t i = (size_t)(b * 256 + t) * 8;
        f32x4 a0 = *(const f32x4*)(X + i);
        f32x4 a1 = *(const f32x4*)(X + i + 4);
        bf16x8 o;
#pragma unroll
        for (int j = 0; j < 4; ++j) { o[j] = (__bf16)a0[j]; o[4 + j] = (__bf16)a1[j]; }
        *(bf16x8*)(Xb + i) = o;
    } else {
        int j = (b - BXG) * 256 + t;
        const float* Ws = (j < NK * 4096) ? W1 : W2;
        __bf16* Wd      = (j < NK * 4096) ? Wt1 : Wt2;
        int i = (j < NK * 4096) ? j : j - NK * 4096;
        int k  = i >> 12;
        int n  = (i >> 6) & 63;
        int ci = i & 63;
        Wd[i] = (__bf16)Ws[k * 4096 + ci * 64 + n];
    }
}

// ---------------------------------------------------------------- fused: counting-sort rank + (k,chunk) bin count
// LDS bin count first; global hist atomic LAST with no trailing barrier so wave
// retirement overlaps atomic latency (round-8 lesson: barrier after the atomic kills it).
__global__ __launch_bounds__(256)
void rank_count(const int* __restrict__ ok, int* __restrict__ hist, int* __restrict__ rank,
                int* __restrict__ bhist, int shiftC, int ncc) {
    __shared__ int lcount[32];
    int p = blockIdx.x * 256 + threadIdx.x;
    int k = p >> 17;                 // uniform per block (256 | 2^17)
    int okp = ok[p];
    int c = okp >> shiftC;
    if (threadIdx.x < ncc) lcount[threadIdx.x] = 0;
    __syncthreads();
    atomicAdd(&lcount[c], 1);
    __syncthreads();
    if (threadIdx.x < ncc) {
        int n = lcount[threadIdx.x];
        if (n > 0) atomicAdd(&bhist[k * ncc + threadIdx.x], n);
    }
    rank[p] = atomicAdd(&hist[okp], 1);   // last: no barrier after
}

// ---------------------------------------------------------------- scans (hist[262144] -> start[])
__global__ __launch_bounds__(256) void scan1(const int* __restrict__ hist, int* __restrict__ start,
                                             int* __restrict__ bsum) {
    __shared__ int sh[256];
    const int b = blockIdx.x, t = threadIdx.x;
    int4 v = *(const int4*)(hist + b * 1024 + t * 4);
    int s0 = v.x, s1 = s0 + v.y, s2 = s1 + v.z, s3 = s2 + v.w;
    sh[t] = s3;
    __syncthreads();
    for (int off = 1; off < 256; off <<= 1) {
        int val = (t >= off) ? sh[t - off] : 0;
        __syncthreads();
        sh[t] += val;
        __syncthreads();
    }
    int excl = (t == 0) ? 0 : sh[t - 1];
    if (t == 255) bsum[b] = sh[255];
    int4 o;
    o.x = excl; o.y = excl + s0; o.z = excl + s1; o.w = excl + s2;
    *(int4*)(start + b * 1024 + t * 4) = o;
}

__global__ __launch_bounds__(256) void scan2(int* __restrict__ bsum) {
    __shared__ int sh[256];
    const int t = threadIdx.x;
    sh[t] = bsum[t];
    __syncthreads();
    for (int off = 1; off < 256; off <<= 1) {
        int val = (t >= off) ? sh[t - off] : 0;
        __syncthreads();
        sh[t] += val;
        __syncthreads();
    }
    bsum[t] = (t == 0) ? 0 : sh[t - 1];
}

__global__ __launch_bounds__(256) void scan3(int* __restrict__ start, const int* __restrict__ bsum) {
    const int b = blockIdx.x, t = threadIdx.x;
    int add = bsum[b];
    int4 v = *(int4*)(start + b * 1024 + t * 4);
    v.x += add; v.y += add; v.z += add; v.w += add;
    *(int4*)(start + b * 1024 + t * 4) = v;
    if (b == 0 && t == 0) start[NNODES] = NPAIR;
}

// exclusive scan of bhist[NB] (NB <= 864), 1 block of 1024
__global__ __launch_bounds__(1024) void bin_scan(const int* __restrict__ bhist,
                                                 int* __restrict__ bstart, int NB) {
    __shared__ int sh[1024];
    const int t = threadIdx.x;
    int own = (t < NB) ? bhist[t] : 0;
    sh[t] = own;
    __syncthreads();
    for (int off = 1; off < 1024; off <<= 1) {
        int val = (t >= off) ? sh[t - off] : 0;
        __syncthreads();
        sh[t] += val;
        __syncthreads();
    }
    if (t < NB) bstart[t] = sh[t] - own;
    if (t == 0) bstart[NB] = NPAIR;
}

// compact records (perm computed inline): cin[rec]=in node, cslot[rec]=msg slot within chunk
__global__ __launch_bounds__(256) void bin_fill(const int* __restrict__ ik, const int* __restrict__ ok,
                                                const int* __restrict__ rank, const int* __restrict__ start,
                                                const int* __restrict__ bstart, int* __restrict__ bhist2,
                                                int* __restrict__ cin, int* __restrict__ cslot,
                                                int shiftC, int ncc) {
    __shared__ int lcount[32];
    __shared__ int lbase[32];
    int p = blockIdx.x * 256 + threadIdx.x;
    int k = p >> 17;
    int okp = ok[p];
    int c = okp >> shiftC;
    if (threadIdx.x < ncc) lcount[threadIdx.x] = 0;
    __syncthreads();
    int pos = atomicAdd(&lcount[c], 1);
    __syncthreads();
    if (threadIdx.x < ncc) {
        int n = lcount[threadIdx.x];
        lbase[threadIdx.x] = (n > 0) ? atomicAdd(&bhist2[k * ncc + threadIdx.x], n) : 0;
    }
    __syncthreads();
    int rec = bstart[k * ncc + c] + lbase[c] + pos;
    cin[rec]   = ik[p];
    cslot[rec] = start[okp] + rank[p] - start[c << shiftC];
}

// ---------------------------------------------------------------- phase A: gather -> MFMA -> write msg row
template <bool BN>
__global__ __launch_bounds__(256)
void phaseA(const __bf16* __restrict__ Xb, const __bf16* __restrict__ Wt,
            const int* __restrict__ cin, const int* __restrict__ cslot,
            const int* __restrict__ bstart, const float* __restrict__ st,
            __bf16* __restrict__ msg, int ncc, int chunk, int capr) {
    const int k   = blockIdx.y;
    const int bin = k * ncc + chunk;
    const int b0  = bstart[bin];
    const int b1  = bstart[bin + 1];
    const int base = b0 + blockIdx.x * (TILE * TPB);
    if (base >= b1) return;

    const int tid  = threadIdx.x;
    const int wave = tid >> 6;
    const int lane = tid & 63;
    const int l15  = lane & 15;
    const int l4   = lane >> 4;

    __shared__ __align__(16) __bf16 As[64 * 64];
    __shared__ __align__(16) __bf16 Cs[64 * 64];
    __shared__ float s_s[64], s_t[64];

    if (BN && tid < 64) { s_s[tid] = st[tid]; s_t[tid] = st[64 + tid]; }

    bf16x8 bfrag[4][2];
    const __bf16* Wk = Wt + k * 4096;
#pragma unroll
    for (int nt = 0; nt < 4; ++nt)
#pragma unroll
        for (int ks = 0; ks < 2; ++ks)
            bfrag[nt][ks] = *(const bf16x8*)(Wk + (nt * 16 + l15) * 64 + ks * 32 + l4 * 8);

    const int r = tid >> 2;   // row in 64-row tile
    const int q = tid & 3;    // 16-channel segment
    char* Ab = (char*)As;
    char* Cb = (char*)Cs;
    const int rb = wave * 16;

    __syncthreads();   // s_s / bfrag ordering

    for (int t = 0; t < TPB; ++t) {
        const int p0 = base + t * TILE;
        if (p0 >= b1) break;                      // uniform across block
        const int rec   = p0 + r;
        const bool valid = rec < b1;
        const int gidx = valid ? cin[rec] : 0;
        const int slot = valid ? cslot[rec] : capr + r;   // trash rows

        const __bf16* xr = Xb + (size_t)gidx * 64 + q * 16;
        bf16x8 c0 = *(const bf16x8*)xr;
        bf16x8 c1 = *(const bf16x8*)(xr + 8);
        if (BN) {
            const int cb = q * 16;
#pragma unroll
            for (int j = 0; j < 8; ++j) {
                float v0 = (float)c0[j], v1 = (float)c1[j];
                c0[j] = (__bf16)fmaxf(fmaf(v0, s_s[cb + j],     s_t[cb + j]),     0.0f);
                c1[j] = (__bf16)fmaxf(fmaf(v1, s_s[cb + 8 + j], s_t[cb + 8 + j]), 0.0f);
            }
        }
        *(bf16x8*)(Ab + r * 128 + (((2 * q)     ^ (r & 7)) << 4)) = c0;
        *(bf16x8*)(Ab + r * 128 + (((2 * q + 1) ^ (r & 7)) << 4)) = c1;
        __syncthreads();

        f32x4 acc[4];
#pragma unroll
        for (int nt = 0; nt < 4; ++nt)
#pragma unroll
            for (int j = 0; j < 4; ++j) acc[nt][j] = 0.0f;
#pragma unroll
        for (int ks = 0; ks < 2; ++ks) {
            const int row = rb + l15;
            bf16x8 a = *(const bf16x8*)(Ab + row * 128 + ((((ks << 2) + l4) ^ (row & 7)) << 4));
#pragma unroll
            for (int nt = 0; nt < 4; ++nt)
                acc[nt] = __builtin_amdgcn_mfma_f32_16x16x32_bf16(a, bfrag[nt][ks], acc[nt], 0, 0, 0);
        }

        // repack D fragments -> Cs (swizzled 16B chunks), bf16
#pragma unroll
        for (int rg = 0; rg < 4; ++rg) {
            const int row = rb + l4 * 4 + rg;
            char* cr = Cb + row * 128;
#pragma unroll
            for (int nt = 0; nt < 4; ++nt) {
                const int ch = nt * 2 + (l15 >> 3);
                *(__bf16*)(cr + ((ch ^ (row & 7)) << 4) + (l15 & 7) * 2) = (__bf16)acc[nt][rg];
            }
        }
        __syncthreads();

        bf16x8 o0 = *(bf16x8*)(Cb + r * 128 + (((2 * q)     ^ (r & 7)) << 4));
        bf16x8 o1 = *(bf16x8*)(Cb + r * 128 + (((2 * q + 1) ^ (r & 7)) << 4));
        __bf16* mr = msg + (size_t)slot * 64 + q * 16;
        *(bf16x8*)mr       = o0;
        *(bf16x8*)(mr + 8) = o1;
    }
}

// ---------------------------------------------------------------- phase B: wide segment sum (2x unroll) + BN partials
template <bool FIRST>
__global__ __launch_bounds__(256)
void phaseB(const __bf16* __restrict__ msg, const int* __restrict__ start,
            int cbase, int nodesC,
            __bf16* __restrict__ outb, float* __restrict__ outf, float* __restrict__ psum) {
    const int wave = threadIdx.x >> 6;
    const int lane = threadIdx.x & 63;
    const int rs   = lane >> 3;    // row slice 0..7
    const int g    = lane & 7;     // channel group (8 channels)
    const int slotbase = start[cbase];
    float s[8], s2[8];
#pragma unroll
    for (int j = 0; j < 8; ++j) { s[j] = 0.0f; s2[j] = 0.0f; }

    for (int n0 = blockIdx.x * 4 + wave; n0 < nodesC; n0 += gridDim.x * 4) {
        const int n = cbase + n0;
        const int b = start[n] - slotbase;
        const int deg = start[n + 1] - slotbase - b;
        float acc[8];
#pragma unroll
        for (int j = 0; j < 8; ++j) acc[j] = 0.0f;
        int i = rs;
        for (; i + 8 < deg; i += 16) {
            bf16x8 v0 = *(const bf16x8*)(msg + (size_t)(b + i) * 64 + g * 8);
            bf16x8 v1 = *(const bf16x8*)(msg + (size_t)(b + i + 8) * 64 + g * 8);
#pragma unroll
            for (int j = 0; j < 8; ++j) acc[j] += (float)v0[j] + (float)v1[j];
        }
        if (i < deg) {
            bf16x8 v0 = *(const bf16x8*)(msg + (size_t)(b + i) * 64 + g * 8);
#pragma unroll
            for (int j = 0; j < 8; ++j) acc[j] += (float)v0[j];
        }
#pragma unroll
        for (int j = 0; j < 8; ++j) {
            acc[j] += __shfl_xor(acc[j], 8);
            acc[j] += __shfl_xor(acc[j], 16);
            acc[j] += __shfl_xor(acc[j], 32);
        }
        if (rs == 0) {
            if (FIRST) {
                bf16x8 o;
#pragma unroll
                for (int j = 0; j < 8; ++j) o[j] = (__bf16)acc[j];
                *(bf16x8*)(outb + (size_t)n * 64 + g * 8) = o;
            } else {
                f32x4 o0, o1;
#pragma unroll
                for (int j = 0; j < 4; ++j) { o0[j] = acc[j]; o1[j] = acc[4 + j]; }
                *(f32x4*)(outf + (size_t)n * 64 + g * 8)     = o0;
                *(f32x4*)(outf + (size_t)n * 64 + g * 8 + 4) = o1;
            }
#pragma unroll
            for (int j = 0; j < 8; ++j) { s[j] += acc[j]; s2[j] += acc[j] * acc[j]; }
        }
    }

    __shared__ float reds[4][64], reds2[4][64];
    if (rs == 0) {
#pragma unroll
        for (int j = 0; j < 8; ++j) { reds[wave][g * 8 + j] = s[j]; reds2[wave][g * 8 + j] = s2[j]; }
    }
    __syncthreads();
    if (threadIdx.x < 64) {
        const int c = threadIdx.x;
        float ts  = reds[0][c] + reds[1][c] + reds[2][c] + reds[3][c];
        float ts2 = reds2[0][c] + reds2[1][c] + reds2[2][c] + reds2[3][c];
        float* pr = psum + (size_t)blockIdx.x * 128;
        pr[c]      += ts;    // owner-block accumulation across chunk launches
        pr[64 + c] += ts2;
    }
}

// ---------------------------------------------------------------- reduce psum[BGRID][128] -> sums[128]
__global__ __launch_bounds__(256) void bn_reduce(const float* __restrict__ psum, float* __restrict__ sums) {
    const int m = blockIdx.x;
    float s = 0.0f;
    for (int b = threadIdx.x; b < BGRID; b += 256) s += psum[(size_t)b * 128 + m];
    __shared__ float sh[256];
    sh[threadIdx.x] = s;
    __syncthreads();
    for (int off = 128; off > 0; off >>= 1) {
        if (threadIdx.x < off) sh[threadIdx.x] += sh[threadIdx.x + off];
        __syncthreads();
    }
    if (threadIdx.x == 0) sums[m] = sh[0];
}

// ---------------------------------------------------------------- BN params
__global__ void bn_params(const float* __restrict__ sums, const float* __restrict__ gamma,
                          const float* __restrict__ beta, float* __restrict__ st) {
    int c = threadIdx.x;
    const float inv = 1.0f / (float)NNODES;
    float mean = sums[c] * inv;
    float var  = sums[64 + c] * inv - mean * mean;
    float s    = gamma[c] * rsqrtf(var + EPSV);
    st[c]      = s;
    st[64 + c] = beta[c] - mean * s;
}

// ---------------------------------------------------------------- final: out = relu(h2*s + t + x)
__global__ __launch_bounds__(256)
void final_kernel(float* __restrict__ Out, const float* __restrict__ X, const float* __restrict__ st) {
    __shared__ float s_s[64], s_t[64];
    if (threadIdx.x < 64) { s_s[threadIdx.x] = st[threadIdx.x]; s_t[threadIdx.x] = st[64 + threadIdx.x]; }
    __syncthreads();
    int i = blockIdx.x * 256 + threadIdx.x;
    f32x4 h  = *(f32x4*)(Out + (size_t)i * 4);
    f32x4 xv = *(const f32x4*)(X + (size_t)i * 4);
    const int cb = (i & 15) * 4;
    f32x4 o;
#pragma unroll
    for (int j = 0; j < 4; ++j)
        o[j] = fmaxf(fmaf(h[j], s_s[cb + j], s_t[cb + j]) + xv[j], 0.0f);
    *(f32x4*)(Out + (size_t)i * 4) = o;
}

// ================================================================ fallback (atomic path)
template <bool BN>
__global__ __launch_bounds__(256)
void conv_kernel(const float* __restrict__ X, const __bf16* __restrict__ Wt,
                 const int* __restrict__ in_idx, const int* __restrict__ out_idx,
                 const float* __restrict__ st, float* __restrict__ Out) {
    const int k    = blockIdx.y;
    const int tid  = threadIdx.x;
    const int wave = tid >> 6;
    const int lane = tid & 63;
    const int l15  = lane & 15;
    const int l4   = lane >> 4;
    __shared__ __align__(16) __bf16 As[64 * 64];
    __shared__ int oks[64];
    __shared__ float s_s[64], s_t[64];
    if (BN && tid < 64) { s_s[tid] = st[tid]; s_t[tid] = st[64 + tid]; }
    bf16x8 bfrag[4][2];
    const __bf16* Wk = Wt + k * 4096;
#pragma unroll
    for (int nt = 0; nt < 4; ++nt)
#pragma unroll
        for (int ks = 0; ks < 2; ++ks)
            bfrag[nt][ks] = *(const bf16x8*)(Wk + (nt * 16 + l15) * 64 + ks * 32 + l4 * 8);
    const int* ik = in_idx + k * NP;
    const int* ok = out_idx + k * NP;
    const int r = tid >> 2;
    const int q = tid & 3;
    char* Abase = (char*)As;
    const int rb = wave * 16;
    __syncthreads();
    int p0 = (blockIdx.x * 8) * 64;
    for (int t = 0; t < 8; ++t, p0 += 64) {
        if (tid < 64) oks[tid] = ok[p0 + tid];
        const float* xr = X + (size_t)ik[p0 + r] * 64 + q * 16;
        f32x4 v0 = *(const f32x4*)(xr + 0);
        f32x4 v1 = *(const f32x4*)(xr + 4);
        f32x4 v2 = *(const f32x4*)(xr + 8);
        f32x4 v3 = *(const f32x4*)(xr + 12);
        float vals[16];
        *(f32x4*)&vals[0]  = v0; *(f32x4*)&vals[4]  = v1;
        *(f32x4*)&vals[8]  = v2; *(f32x4*)&vals[12] = v3;
        if (BN) {
            const int cb = q * 16;
#pragma unroll
            for (int j = 0; j < 16; ++j)
                vals[j] = fmaxf(fmaf(vals[j], s_s[cb + j], s_t[cb + j]), 0.0f);
        }
        bf16x8 c0, c1;
#pragma unroll
        for (int j = 0; j < 8; ++j) { c0[j] = (__bf16)vals[j]; c1[j] = (__bf16)vals[8 + j]; }
        *(bf16x8*)(Abase + r * 128 + (((2 * q)     ^ (r & 7)) << 4)) = c0;
        *(bf16x8*)(Abase + r * 128 + (((2 * q + 1) ^ (r & 7)) << 4)) = c1;
        __syncthreads();
        f32x4 acc[4];
#pragma unroll
        for (int nt = 0; nt < 4; ++nt)
#pragma unroll
            for (int j = 0; j < 4; ++j) acc[nt][j] = 0.0f;
#pragma unroll
        for (int ks = 0; ks < 2; ++ks) {
            const int row = rb + l15;
            bf16x8 a = *(const bf16x8*)(Abase + row * 128 + ((((ks << 2) + l4) ^ (row & 7)) << 4));
#pragma unroll
            for (int nt = 0; nt < 4; ++nt)
                acc[nt] = __builtin_amdgcn_mfma_f32_16x16x32_bf16(a, bfrag[nt][ks], acc[nt], 0, 0, 0);
        }
#pragma unroll
        for (int rg = 0; rg < 4; ++rg) {
            const int rr = rb + l4 * 4 + rg;
            float* orow = Out + (size_t)oks[rr] * 64;
#pragma unroll
            for (int nt = 0; nt < 4; ++nt)
                unsafeAtomicAdd(orow + nt * 16 + l15, acc[nt][rg]);
        }
        __syncthreads();
    }
}

__global__ __launch_bounds__(256)
void bn_stats(const float* __restrict__ H, float* __restrict__ sums) {
    const int c    = threadIdx.x & 63;
    const int slot = threadIdx.x >> 6;
    float s = 0.0f, s2 = 0.0f;
    for (int row = blockIdx.x * 4 + slot; row < NNODES; row += gridDim.x * 4) {
        float v = H[(size_t)row * 64 + c];
        s += v; s2 += v * v;
    }
    __shared__ float red[8][64];
    red[slot][c] = s; red[4 + slot][c] = s2;
    __syncthreads();
    if (slot == 0) {
        s  = red[0][c] + red[1][c] + red[2][c] + red[3][c];
        s2 = red[4][c] + red[5][c] + red[6][c] + red[7][c];
        unsafeAtomicAdd(&sums[c], s);
        unsafeAtomicAdd(&sums[64 + c], s2);
    }
}

// ---------------------------------------------------------------- launch
extern "C" void kernel_launch(void* const* d_in, const int* in_sizes, int n_in,
                              void* d_out, int out_size, void* d_ws, size_t ws_size,
                              hipStream_t stream) {
    const float* x      = (const float*)d_in[0];
    const float* W1     = (const float*)d_in[1];
    // b1 (d_in[2]) cancels through BN1 mean-subtraction — skipped.
    const float* gamma1 = (const float*)d_in[3];
    const float* beta1  = (const float*)d_in[4];
    const float* W2     = (const float*)d_in[5];
    // b2 (d_in[6]) cancels through BN2 — skipped.
    const float* gamma2 = (const float*)d_in[7];
    const float* beta2  = (const float*)d_in[8];
    const int* in_idx   = (const int*)d_in[9];
    const int* out_idx  = (const int*)d_in[10];
    float* out = (float*)d_out;

    char* ws = (char*)d_ws;

    // ---- choose chunk count from ws_size (2 first; ws >= ~310MB proven in round 11)
    auto plan_bytes = [&](int ncc) -> size_t {
        auto rup = [](size_t b) { return (b + 255) & ~(size_t)255; };
        size_t capr = (size_t)NPAIR / ncc + 16384;
        size_t tot = 0;
        tot += rup((capr + 64) * 128);          // msg
        tot += rup((size_t)NNODES * 64 * 2);    // xbf
        tot += rup((size_t)NNODES * 64 * 2);    // h1bf
        tot += rup((size_t)NPAIR * 4);          // rank
        tot += rup((size_t)NPAIR * 4);          // cin
        tot += rup((size_t)NPAIR * 4);          // cslot
        tot += rup((size_t)NNODES * 4);         // hist
        tot += rup((size_t)(NNODES + 64) * 4);  // start
        tot += rup((size_t)NK * ncc * 4) * 2;   // bhist, bhist2
        tot += rup((size_t)(NK * ncc + 1) * 4); // bstart
        tot += rup(1024);                       // bsum
        tot += rup((size_t)NK * 4096 * 2) * 2;  // Wt1, Wt2
        tot += rup((size_t)BGRID * 128 * 4) * 2;// psumA, psumB
        tot += rup(512) * 4;                    // sums/st x2
        return tot;
    };
    int ncc = -1;
    const int cands[5] = {2, 4, 8, 16, 32};
    for (int ci = 0; ci < 5; ++ci)
        if (plan_bytes(cands[ci]) <= ws_size) { ncc = cands[ci]; break; }

    if (ncc > 0) {
        // ---------------- chunked streaming path
        const int shiftC = 18 - __builtin_ctz(ncc);
        const int NB     = NK * ncc;
        const int capr   = NPAIR / ncc + 16384;
        const int nodesC = NNODES / ncc;

        size_t off = 0;
        auto alloc = [&](size_t bytes) -> char* {
            char* p = ws + off;
            off = (off + bytes + 255) & ~(size_t)255;
            return p;
        };
        __bf16* msg    = (__bf16*)alloc((size_t)(capr + 64) * 128);
        __bf16* xbf    = (__bf16*)alloc((size_t)NNODES * 64 * 2);
        __bf16* h1bf   = (__bf16*)alloc((size_t)NNODES * 64 * 2);
        int*    rank   = (int*)alloc((size_t)NPAIR * 4);
        int*    cin    = (int*)alloc((size_t)NPAIR * 4);
        int*    cslot  = (int*)alloc((size_t)NPAIR * 4);
        int*    hist   = (int*)alloc((size_t)NNODES * 4);
        int*    startv = (int*)alloc((size_t)(NNODES + 64) * 4);
        int*    bhist  = (int*)alloc((size_t)NB * 4);
        int*    bhist2 = (int*)alloc((size_t)NB * 4);
        int*    bstart = (int*)alloc((size_t)(NB + 1) * 4);
        int*    bsum   = (int*)alloc(1024);
        __bf16* Wt1    = (__bf16*)alloc((size_t)NK * 4096 * 2);
        __bf16* Wt2    = (__bf16*)alloc((size_t)NK * 4096 * 2);
        float*  psumA  = (float*)alloc((size_t)BGRID * 128 * 4);
        float*  psumB  = (float*)alloc((size_t)BGRID * 128 * 4);
        float*  sums1  = (float*)alloc(512);
        float*  st1    = (float*)alloc(512);
        float*  sums2  = (float*)alloc(512);
        float*  st2    = (float*)alloc(512);

        (void)hipMemsetAsync(hist, 0, (size_t)NNODES * 4, stream);
        (void)hipMemsetAsync(bhist, 0, (size_t)NB * 4, stream);
        (void)hipMemsetAsync(bhist2, 0, (size_t)NB * 4, stream);
        (void)hipMemsetAsync(psumA, 0, (size_t)BGRID * 128 * 4, stream);
        (void)hipMemsetAsync(psumB, 0, (size_t)BGRID * 128 * 4, stream);

        prep_xw<<<BXG + BWG, 256, 0, stream>>>(x, xbf, W1, W2, Wt1, Wt2);
        rank_count<<<NPAIR / 256, 256, 0, stream>>>(out_idx, hist, rank, bhist, shiftC, ncc);
        scan1<<<256, 256, 0, stream>>>(hist, startv, bsum);
        scan2<<<1, 256, 0, stream>>>(bsum);
        scan3<<<256, 256, 0, stream>>>(startv, bsum);
        bin_scan<<<1, 1024, 0, stream>>>(bhist, bstart, NB);
        bin_fill<<<NPAIR / 256, 256, 0, stream>>>(in_idx, out_idx, rank, startv, bstart,
                                                  bhist2, cin, cslot, shiftC, ncc);

        const int meanbin = NP / ncc;
        const int cover   = meanbin + ((meanbin / 8 > 1024) ? meanbin / 8 : 1024);
        const int bx      = (cover + TILE * TPB - 1) / (TILE * TPB);
        dim3 agrid(bx, NK);

        for (int c = 0; c < ncc; ++c) {
            phaseA<false><<<agrid, 256, 0, stream>>>(xbf, Wt1, cin, cslot, bstart,
                                                     nullptr, msg, ncc, c, capr);
            phaseB<true><<<BGRID, 256, 0, stream>>>(msg, startv, c * nodesC, nodesC,
                                                    h1bf, nullptr, psumA);
        }
        bn_reduce<<<128, 256, 0, stream>>>(psumA, sums1);
        bn_params<<<1, 64, 0, stream>>>(sums1, gamma1, beta1, st1);
        for (int c = 0; c < ncc; ++c) {
            phaseA<true><<<agrid, 256, 0, stream>>>(h1bf, Wt2, cin, cslot, bstart,
                                                    st1, msg, ncc, c, capr);
            phaseB<false><<<BGRID, 256, 0, stream>>>(msg, startv, c * nodesC, nodesC,
                                                     nullptr, out, psumB);
        }
        bn_reduce<<<128, 256, 0, stream>>>(psumB, sums2);
        bn_params<<<1, 64, 0, stream>>>(sums2, gamma2, beta2, st2);
        final_kernel<<<NNODES * 64 / 4 / 256, 256, 0, stream>>>(out, x, st2);
    } else {
        // ---------------- fallback: atomic path
        size_t o2 = 0;
        auto alloc2 = [&](size_t bytes) -> char* {
            char* p = ws + o2;
            o2 = (o2 + bytes + 255) & ~(size_t)255;
            return p;
        };
        float*  h1    = (float*)alloc2((size_t)NNODES * 64 * 4);
        float*  fsums1= (float*)alloc2(512);
        float*  fst1  = (float*)alloc2(512);
        float*  fsums2= (float*)alloc2(512);
        float*  fst2  = (float*)alloc2(512);
        __bf16* fWt1  = (__bf16*)alloc2((size_t)NK * 4096 * 2);
        __bf16* fWt2  = (__bf16*)alloc2((size_t)NK * 4096 * 2);

        (void)hipMemsetAsync(h1, 0, (size_t)NNODES * 64 * 4, stream);
        (void)hipMemsetAsync(fsums1, 0, 512, stream);
        (void)hipMemsetAsync(fsums2, 0, 512, stream);
        (void)hipMemsetAsync(d_out, 0, (size_t)out_size * 4, stream);

        prep_w<<<(NK * NC * NC + 255) / 256, 256, 0, stream>>>(W1, fWt1);
        prep_w<<<(NK * NC * NC + 255) / 256, 256, 0, stream>>>(W2, fWt2);
        dim3 cgrid(NP / 64 / 8, NK);
        conv_kernel<false><<<cgrid, 256, 0, stream>>>(x, fWt1, in_idx, out_idx, nullptr, h1);
        bn_stats<<<1024, 256, 0, stream>>>(h1, fsums1);
        bn_params<<<1, 64, 0, stream>>>(fsums1, gamma1, beta1, fst1);
        conv_kernel<true><<<cgrid, 256, 0, stream>>>(h1, fWt2, in_idx, out_idx, fst1, out);
        bn_stats<<<1024, 256, 0, stream>>>(out, fsums2);
        bn_params<<<1, 64, 0, stream>>>(fsums2, gamma2, beta2, fst2);
        final_kernel<<<NNODES * 64 / 4 / 256, 256, 0, stream>>>(out, x, fst2);
    }
}

// Round 14
// 970.079 us; speedup vs baseline: 1.0282x; 1.0282x over previous
//
#include <hip/hip_runtime.h>
#include <hip/hip_bf16.h>

// Sparse BasicBlock: conv1 -> BN1 -> ReLU -> conv2 -> BN2 -> +x -> ReLU
// Chunked atomic-free formulation (ws-adaptive), consolidated best-known (round-12, 978us):
//   prep_xw: x->bf16, W->bf16^T          rank_kernel: counting-sort ranks (standalone!)
//   bin_count/scan/bin_fill: compact per-(k,chunk) records (perm inline)
//   per chunk: phaseA = gather bf16 -> MFMA -> write-once msg row (TPB=8)
//              phaseB = wide segment-sum (8rows x 8ch lanes, 2x unroll) + BN partials
// Law (confirmed x4): never fuse work into the contended-atomic pass.
// Fallback: atomic-scatter path if ws_size too small.

#define NNODES 262144
#define NC 64
#define NK 27
#define NP 131072            // pairs per k (2^17)
#define NPAIR (NK * NP)
#define EPSV 1e-5f
#define TILE 64
#define TPB 8
#define BGRID 4096           // phaseB blocks (also psum rows)

typedef float f32x4 __attribute__((ext_vector_type(4)));
typedef __bf16 bf16x8 __attribute__((ext_vector_type(8)));

// ---------------------------------------------------------------- prep: W -> bf16 transposed (fallback)
__global__ void prep_w(const float* __restrict__ W, __bf16* __restrict__ Wt) {
    int i = blockIdx.x * 256 + threadIdx.x;
    if (i >= NK * NC * NC) return;
    int k  = i >> 12;
    int n  = (i >> 6) & 63;
    int ci = i & 63;
    Wt[i] = (__bf16)W[k * 4096 + ci * 64 + n];
}

// ---------------------------------------------------------------- prep: x->bf16 + W1/W2->bf16^T
#define BXG 8192             // NNODES*64/8/256
#define BWG 864              // 2*NK*4096/256
__global__ __launch_bounds__(256)
void prep_xw(const float* __restrict__ X, __bf16* __restrict__ Xb,
             const float* __restrict__ W1, const float* __restrict__ W2,
             __bf16* __restrict__ Wt1, __bf16* __restrict__ Wt2) {
    const int b = blockIdx.x;
    const int t = threadIdx.x;
    if (b < BXG) {
        size_t i = (size_t)(b * 256 + t) * 8;
        f32x4 a0 = *(const f32x4*)(X + i);
        f32x4 a1 = *(const f32x4*)(X + i + 4);
        bf16x8 o;
#pragma unroll
        for (int j = 0; j < 4; ++j) { o[j] = (__bf16)a0[j]; o[4 + j] = (__bf16)a1[j]; }
        *(bf16x8*)(Xb + i) = o;
    } else {
        int j = (b - BXG) * 256 + t;
        const float* Ws = (j < NK * 4096) ? W1 : W2;
        __bf16* Wd      = (j < NK * 4096) ? Wt1 : Wt2;
        int i = (j < NK * 4096) ? j : j - NK * 4096;
        int k  = i >> 12;
        int n  = (i >> 6) & 63;
        int ci = i & 63;
        Wd[i] = (__bf16)Ws[k * 4096 + ci * 64 + n];
    }
}

// ---------------------------------------------------------------- counting sort by out node (standalone — keep pure)
__global__ void rank_kernel(const int* __restrict__ ok, int* __restrict__ hist, int* __restrict__ rank) {
    int i = blockIdx.x * 256 + threadIdx.x;
    rank[i] = atomicAdd(&hist[ok[i]], 1);
}

// ---------------------------------------------------------------- scans (hist[262144] -> start[])
__global__ __launch_bounds__(256) void scan1(const int* __restrict__ hist, int* __restrict__ start,
                                             int* __restrict__ bsum) {
    __shared__ int sh[256];
    const int b = blockIdx.x, t = threadIdx.x;
    int4 v = *(const int4*)(hist + b * 1024 + t * 4);
    int s0 = v.x, s1 = s0 + v.y, s2 = s1 + v.z, s3 = s2 + v.w;
    sh[t] = s3;
    __syncthreads();
    for (int off = 1; off < 256; off <<= 1) {
        int val = (t >= off) ? sh[t - off] : 0;
        __syncthreads();
        sh[t] += val;
        __syncthreads();
    }
    int excl = (t == 0) ? 0 : sh[t - 1];
    if (t == 255) bsum[b] = sh[255];
    int4 o;
    o.x = excl; o.y = excl + s0; o.z = excl + s1; o.w = excl + s2;
    *(int4*)(start + b * 1024 + t * 4) = o;
}

__global__ __launch_bounds__(256) void scan2(int* __restrict__ bsum) {
    __shared__ int sh[256];
    const int t = threadIdx.x;
    sh[t] = bsum[t];
    __syncthreads();
    for (int off = 1; off < 256; off <<= 1) {
        int val = (t >= off) ? sh[t - off] : 0;
        __syncthreads();
        sh[t] += val;
        __syncthreads();
    }
    bsum[t] = (t == 0) ? 0 : sh[t - 1];
}

__global__ __launch_bounds__(256) void scan3(int* __restrict__ start, const int* __restrict__ bsum) {
    const int b = blockIdx.x, t = threadIdx.x;
    int add = bsum[b];
    int4 v = *(int4*)(start + b * 1024 + t * 4);
    v.x += add; v.y += add; v.z += add; v.w += add;
    *(int4*)(start + b * 1024 + t * 4) = v;
    if (b == 0 && t == 0) start[NNODES] = NPAIR;
}

// ---------------------------------------------------------------- bin count by (k, chunk) — LDS-aggregated
__global__ __launch_bounds__(256) void bin_count(const int* __restrict__ ok, int* __restrict__ bhist,
                                                 int shiftC, int ncc) {
    __shared__ int lcount[32];
    int p = blockIdx.x * 256 + threadIdx.x;
    int k = p >> 17;
    int c = ok[p] >> shiftC;
    if (threadIdx.x < ncc) lcount[threadIdx.x] = 0;
    __syncthreads();
    atomicAdd(&lcount[c], 1);
    __syncthreads();
    if (threadIdx.x < ncc) {
        int n = lcount[threadIdx.x];
        if (n > 0) atomicAdd(&bhist[k * ncc + threadIdx.x], n);
    }
}

// exclusive scan of bhist[NB] (NB <= 864), 1 block of 1024
__global__ __launch_bounds__(1024) void bin_scan(const int* __restrict__ bhist,
                                                 int* __restrict__ bstart, int NB) {
    __shared__ int sh[1024];
    const int t = threadIdx.x;
    int own = (t < NB) ? bhist[t] : 0;
    sh[t] = own;
    __syncthreads();
    for (int off = 1; off < 1024; off <<= 1) {
        int val = (t >= off) ? sh[t - off] : 0;
        __syncthreads();
        sh[t] += val;
        __syncthreads();
    }
    if (t < NB) bstart[t] = sh[t] - own;
    if (t == 0) bstart[NB] = NPAIR;
}

// compact records (perm computed inline): cin[rec]=in node, cslot[rec]=msg slot within chunk
__global__ __launch_bounds__(256) void bin_fill(const int* __restrict__ ik, const int* __restrict__ ok,
                                                const int* __restrict__ rank, const int* __restrict__ start,
                                                const int* __restrict__ bstart, int* __restrict__ bhist2,
                                                int* __restrict__ cin, int* __restrict__ cslot,
                                                int shiftC, int ncc) {
    __shared__ int lcount[32];
    __shared__ int lbase[32];
    int p = blockIdx.x * 256 + threadIdx.x;
    int k = p >> 17;
    int okp = ok[p];
    int c = okp >> shiftC;
    if (threadIdx.x < ncc) lcount[threadIdx.x] = 0;
    __syncthreads();
    int pos = atomicAdd(&lcount[c], 1);
    __syncthreads();
    if (threadIdx.x < ncc) {
        int n = lcount[threadIdx.x];
        lbase[threadIdx.x] = (n > 0) ? atomicAdd(&bhist2[k * ncc + threadIdx.x], n) : 0;
    }
    __syncthreads();
    int rec = bstart[k * ncc + c] + lbase[c] + pos;
    cin[rec]   = ik[p];
    cslot[rec] = start[okp] + rank[p] - start[c << shiftC];
}

// ---------------------------------------------------------------- phase A: gather -> MFMA -> write msg row
template <bool BN>
__global__ __launch_bounds__(256)
void phaseA(const __bf16* __restrict__ Xb, const __bf16* __restrict__ Wt,
            const int* __restrict__ cin, const int* __restrict__ cslot,
            const int* __restrict__ bstart, const float* __restrict__ st,
            __bf16* __restrict__ msg, int ncc, int chunk, int capr) {
    const int k   = blockIdx.y;
    const int bin = k * ncc + chunk;
    const int b0  = bstart[bin];
    const int b1  = bstart[bin + 1];
    const int base = b0 + blockIdx.x * (TILE * TPB);
    if (base >= b1) return;

    const int tid  = threadIdx.x;
    const int wave = tid >> 6;
    const int lane = tid & 63;
    const int l15  = lane & 15;
    const int l4   = lane >> 4;

    __shared__ __align__(16) __bf16 As[64 * 64];
    __shared__ __align__(16) __bf16 Cs[64 * 64];
    __shared__ float s_s[64], s_t[64];

    if (BN && tid < 64) { s_s[tid] = st[tid]; s_t[tid] = st[64 + tid]; }

    bf16x8 bfrag[4][2];
    const __bf16* Wk = Wt + k * 4096;
#pragma unroll
    for (int nt = 0; nt < 4; ++nt)
#pragma unroll
        for (int ks = 0; ks < 2; ++ks)
            bfrag[nt][ks] = *(const bf16x8*)(Wk + (nt * 16 + l15) * 64 + ks * 32 + l4 * 8);

    const int r = tid >> 2;   // row in 64-row tile
    const int q = tid & 3;    // 16-channel segment
    char* Ab = (char*)As;
    char* Cb = (char*)Cs;
    const int rb = wave * 16;

    __syncthreads();   // s_s / bfrag ordering

    for (int t = 0; t < TPB; ++t) {
        const int p0 = base + t * TILE;
        if (p0 >= b1) break;                      // uniform across block
        const int rec   = p0 + r;
        const bool valid = rec < b1;
        const int gidx = valid ? cin[rec] : 0;
        const int slot = valid ? cslot[rec] : capr + r;   // trash rows

        const __bf16* xr = Xb + (size_t)gidx * 64 + q * 16;
        bf16x8 c0 = *(const bf16x8*)xr;
        bf16x8 c1 = *(const bf16x8*)(xr + 8);
        if (BN) {
            const int cb = q * 16;
#pragma unroll
            for (int j = 0; j < 8; ++j) {
                float v0 = (float)c0[j], v1 = (float)c1[j];
                c0[j] = (__bf16)fmaxf(fmaf(v0, s_s[cb + j],     s_t[cb + j]),     0.0f);
                c1[j] = (__bf16)fmaxf(fmaf(v1, s_s[cb + 8 + j], s_t[cb + 8 + j]), 0.0f);
            }
        }
        *(bf16x8*)(Ab + r * 128 + (((2 * q)     ^ (r & 7)) << 4)) = c0;
        *(bf16x8*)(Ab + r * 128 + (((2 * q + 1) ^ (r & 7)) << 4)) = c1;
        __syncthreads();

        f32x4 acc[4];
#pragma unroll
        for (int nt = 0; nt < 4; ++nt)
#pragma unroll
            for (int j = 0; j < 4; ++j) acc[nt][j] = 0.0f;
#pragma unroll
        for (int ks = 0; ks < 2; ++ks) {
            const int row = rb + l15;
            bf16x8 a = *(const bf16x8*)(Ab + row * 128 + ((((ks << 2) + l4) ^ (row & 7)) << 4));
#pragma unroll
            for (int nt = 0; nt < 4; ++nt)
                acc[nt] = __builtin_amdgcn_mfma_f32_16x16x32_bf16(a, bfrag[nt][ks], acc[nt], 0, 0, 0);
        }

        // repack D fragments -> Cs (swizzled 16B chunks), bf16
#pragma unroll
        for (int rg = 0; rg < 4; ++rg) {
            const int row = rb + l4 * 4 + rg;
            char* cr = Cb + row * 128;
#pragma unroll
            for (int nt = 0; nt < 4; ++nt) {
                const int ch = nt * 2 + (l15 >> 3);
                *(__bf16*)(cr + ((ch ^ (row & 7)) << 4) + (l15 & 7) * 2) = (__bf16)acc[nt][rg];
            }
        }
        __syncthreads();

        bf16x8 o0 = *(bf16x8*)(Cb + r * 128 + (((2 * q)     ^ (r & 7)) << 4));
        bf16x8 o1 = *(bf16x8*)(Cb + r * 128 + (((2 * q + 1) ^ (r & 7)) << 4));
        __bf16* mr = msg + (size_t)slot * 64 + q * 16;
        *(bf16x8*)mr       = o0;
        *(bf16x8*)(mr + 8) = o1;
    }
}

// ---------------------------------------------------------------- phase B: wide segment sum (2x unroll) + BN partials
template <bool FIRST>
__global__ __launch_bounds__(256)
void phaseB(const __bf16* __restrict__ msg, const int* __restrict__ start,
            int cbase, int nodesC,
            __bf16* __restrict__ outb, float* __restrict__ outf, float* __restrict__ psum) {
    const int wave = threadIdx.x >> 6;
    const int lane = threadIdx.x & 63;
    const int rs   = lane >> 3;    // row slice 0..7
    const int g    = lane & 7;     // channel group (8 channels)
    const int slotbase = start[cbase];
    float s[8], s2[8];
#pragma unroll
    for (int j = 0; j < 8; ++j) { s[j] = 0.0f; s2[j] = 0.0f; }

    for (int n0 = blockIdx.x * 4 + wave; n0 < nodesC; n0 += gridDim.x * 4) {
        const int n = cbase + n0;
        const int b = start[n] - slotbase;
        const int deg = start[n + 1] - slotbase - b;
        float acc[8];
#pragma unroll
        for (int j = 0; j < 8; ++j) acc[j] = 0.0f;
        int i = rs;
        for (; i + 8 < deg; i += 16) {
            bf16x8 v0 = *(const bf16x8*)(msg + (size_t)(b + i) * 64 + g * 8);
            bf16x8 v1 = *(const bf16x8*)(msg + (size_t)(b + i + 8) * 64 + g * 8);
#pragma unroll
            for (int j = 0; j < 8; ++j) acc[j] += (float)v0[j] + (float)v1[j];
        }
        if (i < deg) {
            bf16x8 v0 = *(const bf16x8*)(msg + (size_t)(b + i) * 64 + g * 8);
#pragma unroll
            for (int j = 0; j < 8; ++j) acc[j] += (float)v0[j];
        }
#pragma unroll
        for (int j = 0; j < 8; ++j) {
            acc[j] += __shfl_xor(acc[j], 8);
            acc[j] += __shfl_xor(acc[j], 16);
            acc[j] += __shfl_xor(acc[j], 32);
        }
        if (rs == 0) {
            if (FIRST) {
                bf16x8 o;
#pragma unroll
                for (int j = 0; j < 8; ++j) o[j] = (__bf16)acc[j];
                *(bf16x8*)(outb + (size_t)n * 64 + g * 8) = o;
            } else {
                f32x4 o0, o1;
#pragma unroll
                for (int j = 0; j < 4; ++j) { o0[j] = acc[j]; o1[j] = acc[4 + j]; }
                *(f32x4*)(outf + (size_t)n * 64 + g * 8)     = o0;
                *(f32x4*)(outf + (size_t)n * 64 + g * 8 + 4) = o1;
            }
#pragma unroll
            for (int j = 0; j < 8; ++j) { s[j] += acc[j]; s2[j] += acc[j] * acc[j]; }
        }
    }

    __shared__ float reds[4][64], reds2[4][64];
    if (rs == 0) {
#pragma unroll
        for (int j = 0; j < 8; ++j) { reds[wave][g * 8 + j] = s[j]; reds2[wave][g * 8 + j] = s2[j]; }
    }
    __syncthreads();
    if (threadIdx.x < 64) {
        const int c = threadIdx.x;
        float ts  = reds[0][c] + reds[1][c] + reds[2][c] + reds[3][c];
        float ts2 = reds2[0][c] + reds2[1][c] + reds2[2][c] + reds2[3][c];
        float* pr = psum + (size_t)blockIdx.x * 128;
        pr[c]      += ts;    // owner-block accumulation across chunk launches
        pr[64 + c] += ts2;
    }
}

// ---------------------------------------------------------------- reduce psum[BGRID][128] -> sums[128]
__global__ __launch_bounds__(256) void bn_reduce(const float* __restrict__ psum, float* __restrict__ sums) {
    const int m = blockIdx.x;
    float s = 0.0f;
    for (int b = threadIdx.x; b < BGRID; b += 256) s += psum[(size_t)b * 128 + m];
    __shared__ float sh[256];
    sh[threadIdx.x] = s;
    __syncthreads();
    for (int off = 128; off > 0; off >>= 1) {
        if (threadIdx.x < off) sh[threadIdx.x] += sh[threadIdx.x + off];
        __syncthreads();
    }
    if (threadIdx.x == 0) sums[m] = sh[0];
}

// ---------------------------------------------------------------- BN params
__global__ void bn_params(const float* __restrict__ sums, const float* __restrict__ gamma,
                          const float* __restrict__ beta, float* __restrict__ st) {
    int c = threadIdx.x;
    const float inv = 1.0f / (float)NNODES;
    float mean = sums[c] * inv;
    float var  = sums[64 + c] * inv - mean * mean;
    float s    = gamma[c] * rsqrtf(var + EPSV);
    st[c]      = s;
    st[64 + c] = beta[c] - mean * s;
}

// ---------------------------------------------------------------- final: out = relu(h2*s + t + x)
__global__ __launch_bounds__(256)
void final_kernel(float* __restrict__ Out, const float* __restrict__ X, const float* __restrict__ st) {
    __shared__ float s_s[64], s_t[64];
    if (threadIdx.x < 64) { s_s[threadIdx.x] = st[threadIdx.x]; s_t[threadIdx.x] = st[64 + threadIdx.x]; }
    __syncthreads();
    int i = blockIdx.x * 256 + threadIdx.x;
    f32x4 h  = *(f32x4*)(Out + (size_t)i * 4);
    f32x4 xv = *(const f32x4*)(X + (size_t)i * 4);
    const int cb = (i & 15) * 4;
    f32x4 o;
#pragma unroll
    for (int j = 0; j < 4; ++j)
        o[j] = fmaxf(fmaf(h[j], s_s[cb + j], s_t[cb + j]) + xv[j], 0.0f);
    *(f32x4*)(Out + (size_t)i * 4) = o;
}

// ================================================================ fallback (atomic path)
template <bool BN>
__global__ __launch_bounds__(256)
void conv_kernel(const float* __restrict__ X, const __bf16* __restrict__ Wt,
                 const int* __restrict__ in_idx, const int* __restrict__ out_idx,
                 const float* __restrict__ st, float* __restrict__ Out) {
    const int k    = blockIdx.y;
    const int tid  = threadIdx.x;
    const int wave = tid >> 6;
    const int lane = tid & 63;
    const int l15  = lane & 15;
    const int l4   = lane >> 4;
    __shared__ __align__(16) __bf16 As[64 * 64];
    __shared__ int oks[64];
    __shared__ float s_s[64], s_t[64];
    if (BN && tid < 64) { s_s[tid] = st[tid]; s_t[tid] = st[64 + tid]; }
    bf16x8 bfrag[4][2];
    const __bf16* Wk = Wt + k * 4096;
#pragma unroll
    for (int nt = 0; nt < 4; ++nt)
#pragma unroll
        for (int ks = 0; ks < 2; ++ks)
            bfrag[nt][ks] = *(const bf16x8*)(Wk + (nt * 16 + l15) * 64 + ks * 32 + l4 * 8);
    const int* ik = in_idx + k * NP;
    const int* ok = out_idx + k * NP;
    const int r = tid >> 2;
    const int q = tid & 3;
    char* Abase = (char*)As;
    const int rb = wave * 16;
    __syncthreads();
    int p0 = (blockIdx.x * 8) * 64;
    for (int t = 0; t < 8; ++t, p0 += 64) {
        if (tid < 64) oks[tid] = ok[p0 + tid];
        const float* xr = X + (size_t)ik[p0 + r] * 64 + q * 16;
        f32x4 v0 = *(const f32x4*)(xr + 0);
        f32x4 v1 = *(const f32x4*)(xr + 4);
        f32x4 v2 = *(const f32x4*)(xr + 8);
        f32x4 v3 = *(const f32x4*)(xr + 12);
        float vals[16];
        *(f32x4*)&vals[0]  = v0; *(f32x4*)&vals[4]  = v1;
        *(f32x4*)&vals[8]  = v2; *(f32x4*)&vals[12] = v3;
        if (BN) {
            const int cb = q * 16;
#pragma unroll
            for (int j = 0; j < 16; ++j)
                vals[j] = fmaxf(fmaf(vals[j], s_s[cb + j], s_t[cb + j]), 0.0f);
        }
        bf16x8 c0, c1;
#pragma unroll
        for (int j = 0; j < 8; ++j) { c0[j] = (__bf16)vals[j]; c1[j] = (__bf16)vals[8 + j]; }
        *(bf16x8*)(Abase + r * 128 + (((2 * q)     ^ (r & 7)) << 4)) = c0;
        *(bf16x8*)(Abase + r * 128 + (((2 * q + 1) ^ (r & 7)) << 4)) = c1;
        __syncthreads();
        f32x4 acc[4];
#pragma unroll
        for (int nt = 0; nt < 4; ++nt)
#pragma unroll
            for (int j = 0; j < 4; ++j) acc[nt][j] = 0.0f;
#pragma unroll
        for (int ks = 0; ks < 2; ++ks) {
            const int row = rb + l15;
            bf16x8 a = *(const bf16x8*)(Abase + row * 128 + ((((ks << 2) + l4) ^ (row & 7)) << 4));
#pragma unroll
            for (int nt = 0; nt < 4; ++nt)
                acc[nt] = __builtin_amdgcn_mfma_f32_16x16x32_bf16(a, bfrag[nt][ks], acc[nt], 0, 0, 0);
        }
#pragma unroll
        for (int rg = 0; rg < 4; ++rg) {
            const int rr = rb + l4 * 4 + rg;
            float* orow = Out + (size_t)oks[rr] * 64;
#pragma unroll
            for (int nt = 0; nt < 4; ++nt)
                unsafeAtomicAdd(orow + nt * 16 + l15, acc[nt][rg]);
        }
        __syncthreads();
    }
}

__global__ __launch_bounds__(256)
void bn_stats(const float* __restrict__ H, float* __restrict__ sums) {
    const int c    = threadIdx.x & 63;
    const int slot = threadIdx.x >> 6;
    float s = 0.0f, s2 = 0.0f;
    for (int row = blockIdx.x * 4 + slot; row < NNODES; row += gridDim.x * 4) {
        float v = H[(size_t)row * 64 + c];
        s += v; s2 += v * v;
    }
    __shared__ float red[8][64];
    red[slot][c] = s; red[4 + slot][c] = s2;
    __syncthreads();
    if (slot == 0) {
        s  = red[0][c] + red[1][c] + red[2][c] + red[3][c];
        s2 = red[4][c] + red[5][c] + red[6][c] + red[7][c];
        unsafeAtomicAdd(&sums[c], s);
        unsafeAtomicAdd(&sums[64 + c], s2);
    }
}

// ---------------------------------------------------------------- launch
extern "C" void kernel_launch(void* const* d_in, const int* in_sizes, int n_in,
                              void* d_out, int out_size, void* d_ws, size_t ws_size,
                              hipStream_t stream) {
    const float* x      = (const float*)d_in[0];
    const float* W1     = (const float*)d_in[1];
    // b1 (d_in[2]) cancels through BN1 mean-subtraction — skipped.
    const float* gamma1 = (const float*)d_in[3];
    const float* beta1  = (const float*)d_in[4];
    const float* W2     = (const float*)d_in[5];
    // b2 (d_in[6]) cancels through BN2 — skipped.
    const float* gamma2 = (const float*)d_in[7];
    const float* beta2  = (const float*)d_in[8];
    const int* in_idx   = (const int*)d_in[9];
    const int* out_idx  = (const int*)d_in[10];
    float* out = (float*)d_out;

    char* ws = (char*)d_ws;

    // ---- choose chunk count from ws_size (2 first; ws >= ~310MB proven in round 11)
    auto plan_bytes = [&](int ncc) -> size_t {
        auto rup = [](size_t b) { return (b + 255) & ~(size_t)255; };
        size_t capr = (size_t)NPAIR / ncc + 16384;
        size_t tot = 0;
        tot += rup((capr + 64) * 128);          // msg
        tot += rup((size_t)NNODES * 64 * 2);    // xbf
        tot += rup((size_t)NNODES * 64 * 2);    // h1bf
        tot += rup((size_t)NPAIR * 4);          // rank
        tot += rup((size_t)NPAIR * 4);          // cin
        tot += rup((size_t)NPAIR * 4);          // cslot
        tot += rup((size_t)NNODES * 4);         // hist
        tot += rup((size_t)(NNODES + 64) * 4);  // start
        tot += rup((size_t)NK * ncc * 4) * 2;   // bhist, bhist2
        tot += rup((size_t)(NK * ncc + 1) * 4); // bstart
        tot += rup(1024);                       // bsum
        tot += rup((size_t)NK * 4096 * 2) * 2;  // Wt1, Wt2
        tot += rup((size_t)BGRID * 128 * 4) * 2;// psumA, psumB
        tot += rup(512) * 4;                    // sums/st x2
        return tot;
    };
    int ncc = -1;
    const int cands[5] = {2, 4, 8, 16, 32};
    for (int ci = 0; ci < 5; ++ci)
        if (plan_bytes(cands[ci]) <= ws_size) { ncc = cands[ci]; break; }

    if (ncc > 0) {
        // ---------------- chunked streaming path
        const int shiftC = 18 - __builtin_ctz(ncc);
        const int NB     = NK * ncc;
        const int capr   = NPAIR / ncc + 16384;
        const int nodesC = NNODES / ncc;

        size_t off = 0;
        auto alloc = [&](size_t bytes) -> char* {
            char* p = ws + off;
            off = (off + bytes + 255) & ~(size_t)255;
            return p;
        };
        __bf16* msg    = (__bf16*)alloc((size_t)(capr + 64) * 128);
        __bf16* xbf    = (__bf16*)alloc((size_t)NNODES * 64 * 2);
        __bf16* h1bf   = (__bf16*)alloc((size_t)NNODES * 64 * 2);
        int*    rank   = (int*)alloc((size_t)NPAIR * 4);
        int*    cin    = (int*)alloc((size_t)NPAIR * 4);
        int*    cslot  = (int*)alloc((size_t)NPAIR * 4);
        int*    hist   = (int*)alloc((size_t)NNODES * 4);
        int*    startv = (int*)alloc((size_t)(NNODES + 64) * 4);
        int*    bhist  = (int*)alloc((size_t)NB * 4);
        int*    bhist2 = (int*)alloc((size_t)NB * 4);
        int*    bstart = (int*)alloc((size_t)(NB + 1) * 4);
        int*    bsum   = (int*)alloc(1024);
        __bf16* Wt1    = (__bf16*)alloc((size_t)NK * 4096 * 2);
        __bf16* Wt2    = (__bf16*)alloc((size_t)NK * 4096 * 2);
        float*  psumA  = (float*)alloc((size_t)BGRID * 128 * 4);
        float*  psumB  = (float*)alloc((size_t)BGRID * 128 * 4);
        float*  sums1  = (float*)alloc(512);
        float*  st1    = (float*)alloc(512);
        float*  sums2  = (float*)alloc(512);
        float*  st2    = (float*)alloc(512);

        (void)hipMemsetAsync(hist, 0, (size_t)NNODES * 4, stream);
        (void)hipMemsetAsync(bhist, 0, (size_t)NB * 4, stream);
        (void)hipMemsetAsync(bhist2, 0, (size_t)NB * 4, stream);
        (void)hipMemsetAsync(psumA, 0, (size_t)BGRID * 128 * 4, stream);
        (void)hipMemsetAsync(psumB, 0, (size_t)BGRID * 128 * 4, stream);

        prep_xw<<<BXG + BWG, 256, 0, stream>>>(x, xbf, W1, W2, Wt1, Wt2);
        rank_kernel<<<NPAIR / 256, 256, 0, stream>>>(out_idx, hist, rank);
        bin_count<<<NPAIR / 256, 256, 0, stream>>>(out_idx, bhist, shiftC, ncc);
        scan1<<<256, 256, 0, stream>>>(hist, startv, bsum);
        scan2<<<1, 256, 0, stream>>>(bsum);
        scan3<<<256, 256, 0, stream>>>(startv, bsum);
        bin_scan<<<1, 1024, 0, stream>>>(bhist, bstart, NB);
        bin_fill<<<NPAIR / 256, 256, 0, stream>>>(in_idx, out_idx, rank, startv, bstart,
                                                  bhist2, cin, cslot, shiftC, ncc);

        const int meanbin = NP / ncc;
        const int cover   = meanbin + ((meanbin / 8 > 1024) ? meanbin / 8 : 1024);
        const int bx      = (cover + TILE * TPB - 1) / (TILE * TPB);
        dim3 agrid(bx, NK);

        for (int c = 0; c < ncc; ++c) {
            phaseA<false><<<agrid, 256, 0, stream>>>(xbf, Wt1, cin, cslot, bstart,
                                                     nullptr, msg, ncc, c, capr);
            phaseB<true><<<BGRID, 256, 0, stream>>>(msg, startv, c * nodesC, nodesC,
                                                    h1bf, nullptr, psumA);
        }
        bn_reduce<<<128, 256, 0, stream>>>(psumA, sums1);
        bn_params<<<1, 64, 0, stream>>>(sums1, gamma1, beta1, st1);
        for (int c = 0; c < ncc; ++c) {
            phaseA<true><<<agrid, 256, 0, stream>>>(h1bf, Wt2, cin, cslot, bstart,
                                                    st1, msg, ncc, c, capr);
            phaseB<false><<<BGRID, 256, 0, stream>>>(msg, startv, c * nodesC, nodesC,
                                                     nullptr, out, psumB);
        }
        bn_reduce<<<128, 256, 0, stream>>>(psumB, sums2);
        bn_params<<<1, 64, 0, stream>>>(sums2, gamma2, beta2, st2);
        final_kernel<<<NNODES * 64 / 4 / 256, 256, 0, stream>>>(out, x, st2);
    } else {
        // ---------------- fallback: atomic path
        size_t o2 = 0;
        auto alloc2 = [&](size_t bytes) -> char* {
            char* p = ws + o2;
            o2 = (o2 + bytes + 255) & ~(size_t)255;
            return p;
        };
        float*  h1    = (float*)alloc2((size_t)NNODES * 64 * 4);
        float*  fsums1= (float*)alloc2(512);
        float*  fst1  = (float*)alloc2(512);
        float*  fsums2= (float*)alloc2(512);
        float*  fst2  = (float*)alloc2(512);
        __bf16* fWt1  = (__bf16*)alloc2((size_t)NK * 4096 * 2);
        __bf16* fWt2  = (__bf16*)alloc2((size_t)NK * 4096 * 2);

        (void)hipMemsetAsync(h1, 0, (size_t)NNODES * 64 * 4, stream);
        (void)hipMemsetAsync(fsums1, 0, 512, stream);
        (void)hipMemsetAsync(fsums2, 0, 512, stream);
        (void)hipMemsetAsync(d_out, 0, (size_t)out_size * 4, stream);

        prep_w<<<(NK * NC * NC + 255) / 256, 256, 0, stream>>>(W1, fWt1);
        prep_w<<<(NK * NC * NC + 255) / 256, 256, 0, stream>>>(W2, fWt2);
        dim3 cgrid(NP / 64 / 8, NK);
        conv_kernel<false><<<cgrid, 256, 0, stream>>>(x, fWt1, in_idx, out_idx, nullptr, h1);
        bn_stats<<<1024, 256, 0, stream>>>(h1, fsums1);
        bn_params<<<1, 64, 0, stream>>>(fsums1, gamma1, beta1, fst1);
        conv_kernel<true><<<cgrid, 256, 0, stream>>>(h1, fWt2, in_idx, out_idx, fst1, out);
        bn_stats<<<1024, 256, 0, stream>>>(out, fsums2);
        bn_params<<<1, 64, 0, stream>>>(fsums2, gamma2, beta2, fst2);
        final_kernel<<<NNODES * 64 / 4 / 256, 256, 0, stream>>>(out, x, fst2);
    }
}